// Round 15
// baseline (222.450 us; speedup 1.0000x reference)
//
#include <hip/hip_runtime.h>
#include <cstdint>
#include <cstddef>

#define CD   512
#define BDIM 16
#define NQ   1024
#define NP   1024
#define NUP  2048

typedef unsigned short u16;
typedef short short8 __attribute__((ext_vector_type(8)));
typedef float f32x4  __attribute__((ext_vector_type(4)));
typedef float f32x16 __attribute__((ext_vector_type(16)));
typedef uint32_t u32x4 __attribute__((ext_vector_type(4)));

#define GLOAD16(g, l) __builtin_amdgcn_global_load_lds( \
    (const __attribute__((address_space(1))) void*)(g), \
    (__attribute__((address_space(3))) void*)(l), 16, 0, 0)

__device__ __forceinline__ u16 rne_bf16(float x) {
  uint32_t u = __float_as_uint(x);
  return (u16)((u + 0x7fffu + ((u >> 16) & 1u)) >> 16);
}
__device__ __forceinline__ float bf2f(u16 v) {
  return __uint_as_float(((uint32_t)v) << 16);
}

// ---------------------------------------------------- prep: conversions + 3-NN
__global__ __launch_bounds__(256) void prep_kernel(
    const float* __restrict__ query, u16* __restrict__ Qa,
    const float* __restrict__ key, u16* __restrict__ Ka,
    const float* __restrict__ Wq, const float* __restrict__ Wkv1,
    const float* __restrict__ projw, const float* __restrict__ fpw,
    const float* __restrict__ wkv2, u16* __restrict__ Wq2,
    u16* __restrict__ Wkv12, u16* __restrict__ proj2,
    u16* __restrict__ fpwb, u16* __restrict__ wkv2b,
    const float* __restrict__ key_pos, const float* __restrict__ xyz_up,
    int* __restrict__ idx_out, float* __restrict__ w_out)
{
  const int bx = blockIdx.x;
  const int tid = threadIdx.x;
  if (bx < 8832) {
    const float* in; u16* out; float scl = 1.0f; long u;
    if (bx < 8192) {
      in = (bx < 4096) ? query : key;
      out = (bx < 4096) ? Qa : Ka;
      u = (long)(bx & 4095) * 256 + tid;
    } else {
      const int job = (bx - 8192) >> 7;
      in  = (job == 0) ? Wq  : (job == 1) ? Wkv1  : (job == 2) ? projw : (job == 3) ? fpw  : wkv2;
      out = (job == 0) ? Wq2 : (job == 1) ? Wkv12 : (job == 2) ? proj2 : (job == 3) ? fpwb : wkv2b;
      if (job == 0) scl = 0.18033688011112042f;   // 0.125 * log2(e)
      u = (long)((bx - 8192) & 127) * 256 + tid;
    }
    const float* ip = in + u * 8;
    float v[8];
    *(float4*)&v[0] = *(const float4*)ip;
    *(float4*)&v[4] = *(const float4*)(ip + 4);
    short8 o;
#pragma unroll
    for (int i = 0; i < 8; ++i) o[i] = (short)rne_bf16(v[i] * scl);
    *(short8*)(out + u * 8) = o;
    return;
  }
  // ---- 3-NN: 16 points x 16 scanners x 64 keys, float4 LDS, shfl merge
  __shared__ __align__(16) float4 kp4[NP];
  const int kb = bx - 8832;
  const int b = kb >> 7;
  const int n0 = (kb & 127) * 16;
  const float* kpb = key_pos + (long)b * NP * 3;
#pragma unroll
  for (int s = 0; s < 4; ++s) {
    const int t = s * 256 + tid;
    kp4[t] = make_float4(kpb[t * 3], kpb[t * 3 + 1], kpb[t * 3 + 2], 0.0f);
  }
  __syncthreads();
  const int sc = tid & 15, pt = tid >> 4;
  const int n = n0 + pt;
  const float ux = xyz_up[(b * NUP + n) * 3 + 0];
  const float uy = xyz_up[(b * NUP + n) * 3 + 1];
  const float uz = xyz_up[(b * NUP + n) * 3 + 2];
  float e0 = 3.4e38f, e1 = 3.4e38f, e2 = 3.4e38f;
  int j0 = 0, j1 = 0, j2 = 0;
  for (int it = 0; it < 64; ++it) {
    const int j = it * 16 + sc;
    const float4 kv = kp4[j];
    const float dx = ux - kv.x, dy = uy - kv.y, dz = uz - kv.z;
    const float dd = dx * dx + dy * dy + dz * dz;
    if (dd < e2) {
      if (dd < e1) {
        e2 = e1; j2 = j1;
        if (dd < e0) { e1 = e0; j1 = j0; e0 = dd; j0 = j; }
        else         { e1 = dd; j1 = j; }
      } else { e2 = dd; j2 = j; }
    }
  }
#pragma unroll
  for (int ms = 1; ms <= 8; ms <<= 1) {
    const float pd0 = __shfl_xor(e0, ms), pd1 = __shfl_xor(e1, ms), pd2 = __shfl_xor(e2, ms);
    const int   pi0 = __shfl_xor(j0, ms), pi1 = __shfl_xor(j1, ms), pi2 = __shfl_xor(j2, ms);
    float cd[3] = {pd0, pd1, pd2};
    int   ci[3] = {pi0, pi1, pi2};
#pragma unroll
    for (int t = 0; t < 3; ++t) {
      const float dd = cd[t]; const int jj = ci[t];
      if (dd < e2 || (dd == e2 && jj < j2)) {
        if (dd < e1 || (dd == e1 && jj < j1)) {
          e2 = e1; j2 = j1;
          if (dd < e0 || (dd == e0 && jj < j0)) { e1 = e0; j1 = j0; e0 = dd; j0 = jj; }
          else                                  { e1 = dd; j1 = jj; }
        } else { e2 = dd; j2 = jj; }
      }
    }
  }
  if (sc == 0) {
    const float w0 = 1.0f / (e0 + 1e-8f);
    const float w1 = 1.0f / (e1 + 1e-8f);
    const float w2 = 1.0f / (e2 + 1e-8f);
    const float inv = 1.0f / ((w0 + w1) + w2);
    const long r = (long)b * NUP + n;
    idx_out[r * 3 + 0] = j0; idx_out[r * 3 + 1] = j1; idx_out[r * 3 + 2] = j2;
    w_out[r * 3 + 0] = w0 * inv; w_out[r * 3 + 1] = w1 * inv; w_out[r * 3 + 2] = w2 * inv;
  }
}

// ---------------------------------------------------------------- GEMM BK=64
// OMODE 0: bf16 (M,512); 1: +bias+relu; 2: fp32 +bias transposed rows;
// OMODE 3: V-transpose epilogue -> Vt[((b*4+h)*64+d)*NKT + point], no KV write.
template<int AMODE, int OMODE, int KE, int NKT>
__device__ __forceinline__ void gemm_body64(
    u16* __restrict__ As, u16* __restrict__ Ws,
    const u16* __restrict__ A, const u16* __restrict__ W,
    const float* __restrict__ bias, void* __restrict__ outv,
    u16* __restrict__ Vt, const int m0, const int n0)
{
  const int tid = threadIdx.x;
  const int lane = tid & 63, wv = tid >> 6;
  const int rch = tid & 7;

  f32x4 acc[4][4];
#pragma unroll
  for (int mi = 0; mi < 4; ++mi)
#pragma unroll
    for (int ni = 0; ni < 4; ++ni)
#pragma unroll
      for (int r = 0; r < 4; ++r) acc[mi][ni][r] = 0.0f;

  const long rowb = (long)KE * 2;
  const char* gA[4]; const char* gW[4];
#pragma unroll
  for (int s = 0; s < 4; ++s) {
    const int row = s * 32 + (tid >> 3);
    const int gm = m0 + row;
    const long arow = (AMODE == 0) ? (long)gm : (long)(gm & 15) * 2048 + (gm >> 4);
    const int kb0 = (rch ^ (row & 7)) << 4;
    gA[s] = (const char*)A + arow * rowb + kb0;
    gW[s] = (const char*)W + (long)(n0 + row) * rowb + kb0;
  }
  const int wr = (wv >> 1) * 64, wc = (wv & 1) * 64;
  const int g = lane >> 4, cl = lane & 15;

  for (int kt = 0; kt < KE / 64; ++kt) {
#pragma unroll
    for (int s = 0; s < 4; ++s) {
      GLOAD16(gA[s], (char*)As + (s * 256 + tid) * 16);
      GLOAD16(gW[s], (char*)Ws + (s * 256 + tid) * 16);
      gA[s] += 128; gW[s] += 128;
    }
    __syncthreads();
#pragma unroll
    for (int kb = 0; kb < 2; ++kb) {
      short8 af[4], bf[4];
#pragma unroll
      for (int i = 0; i < 4; ++i) {
        const int ra = wr + i * 16 + cl;
        af[i] = *(const short8*)((const char*)As + ra * 128
                 + ((kb * 64 + g * 16) ^ ((ra & 7) << 4)));
        const int rb = wc + i * 16 + cl;
        bf[i] = *(const short8*)((const char*)Ws + rb * 128
                 + ((kb * 64 + g * 16) ^ ((rb & 7) << 4)));
      }
#pragma unroll
      for (int mi = 0; mi < 4; ++mi)
#pragma unroll
        for (int ni = 0; ni < 4; ++ni)
          acc[mi][ni] = __builtin_amdgcn_mfma_f32_16x16x32_bf16(af[mi], bf[ni], acc[mi][ni], 0, 0, 0);
    }
    __syncthreads();
  }

  if constexpr (OMODE == 3) {
    u16* T = As;
#pragma unroll
    for (int ni = 0; ni < 4; ++ni) {
      const int n = wc + ni * 16 + cl;
      const int swz = (n & 15) << 4;
      const int rb2 = n * 256;
#pragma unroll
      for (int mi = 0; mi < 4; ++mi) {
        uint32_t lo, hi;
        asm("v_cvt_pk_bf16_f32 %0, %1, %2" : "=v"(lo) : "v"(acc[mi][ni][0]), "v"(acc[mi][ni][1]));
        asm("v_cvt_pk_bf16_f32 %0, %1, %2" : "=v"(hi) : "v"(acc[mi][ni][2]), "v"(acc[mi][ni][3]));
        const int m2 = 2 * (wr + mi * 16 + g * 4);
        uint2 pk; pk.x = lo; pk.y = hi;
        *(uint2*)((char*)T + rb2 + (m2 ^ swz)) = pk;
      }
    }
    __syncthreads();
    const int nl = tid >> 1, mh = tid & 1;
    const int v = (n0 - 256) + nl;
    const int hh = v >> 6, dd = v & 63;
    const int bq = m0 / NKT;
    const int p0 = (m0 & (NKT - 1)) + mh * 64;
    u16* dst = Vt + ((size_t)((bq * 4 + hh) * 64 + dd)) * NKT + p0;
    const int swz = (nl & 15) << 4;
#pragma unroll
    for (int j = 0; j < 8; ++j) {
      const int m2 = mh * 128 + j * 16;
      const short8 val = *(const short8*)((const char*)T + nl * 256 + (m2 ^ swz));
      *(short8*)(dst + j * 8) = val;
    }
    return;
  } else {
#pragma unroll
    for (int mi = 0; mi < 4; ++mi)
#pragma unroll
      for (int ni = 0; ni < 4; ++ni)
#pragma unroll
        for (int r = 0; r < 4; ++r) {
          const int gm = m0 + wr + mi * 16 + g * 4 + r;
          const int gn = n0 + wc + ni * 16 + cl;
          float vv = acc[mi][ni][r];
          if (OMODE == 0) {
            ((u16*)outv)[(long)gm * 512 + gn] = rne_bf16(vv);
          } else if (OMODE == 1) {
            vv = fmaxf(vv + bias[gn], 0.0f);
            ((u16*)outv)[(long)gm * 512 + gn] = rne_bf16(vv);
          } else {
            vv += bias[gn];
            ((float*)outv)[((long)(gm & 1023) * BDIM + (gm >> 10)) * 512 + gn] = vv;
          }
        }
  }
}

// panel-XCD swizzle: 4 N-tiles sharing one A-panel land on one XCD.
__device__ __forceinline__ int swz_p(int d)  { return (d & 7) | ((d >> 5) << 3); }
__device__ __forceinline__ int swz_nt(int d) { return (d >> 3) & 3; }

// fp-GEMM: key2 = relu(interp @ fp_w^T + b), 1024 blocks
__global__ __launch_bounds__(256) void gemm_fp_kernel(
    const u16* __restrict__ A, const u16* __restrict__ W,
    const float* __restrict__ bias, u16* __restrict__ outv)
{
  __shared__ __align__(16) u16 SH[16384];
  const int d = blockIdx.x;
  gemm_body64<0, 1, 512, 1024>(SH, SH + 8192, A, W, bias, outv, nullptr,
                               swz_p(d) * 128, swz_nt(d) * 128);
}

// ---------------- L2: q-GEMM (512) + kv1-GEMM w/ Vt1 fold (512) + interp (8192)
__global__ __launch_bounds__(256) void qkv1_interp_kernel(
    const u16* __restrict__ Qa, const u16* __restrict__ Wq2, u16* __restrict__ Qb,
    const u16* __restrict__ Ka, const u16* __restrict__ Wkv12,
    u16* __restrict__ KV1, u16* __restrict__ Vt1,
    const int* __restrict__ idx, const float* __restrict__ w, u16* __restrict__ IN2)
{
  __shared__ __align__(16) u16 SH[16384];
  const int bid = blockIdx.x;
  if (bid < 512) {
    gemm_body64<0, 0, 512, 1024>(SH, SH + 8192, Qa, Wq2, nullptr, Qb, nullptr,
                                 swz_p(bid) * 128, swz_nt(bid) * 128);
  } else if (bid < 1024) {
    const int t = bid - 512;
    const int n0 = swz_nt(t) * 128;
    if (n0 >= 256)
      gemm_body64<0, 3, 512, 1024>(SH, SH + 8192, Ka, Wkv12, nullptr, KV1, Vt1,
                                   swz_p(t) * 128, n0);
    else
      gemm_body64<0, 0, 512, 1024>(SH, SH + 8192, Ka, Wkv12, nullptr, KV1, nullptr,
                                   swz_p(t) * 128, n0);
  } else {
    const int t = threadIdx.x;
    const long r = (long)(bid - 1024) * 4 + (t >> 6);
    const int j = t & 63;
    const int b = (int)(r >> 11);
    const int j0 = idx[r * 3 + 0], j1 = idx[r * 3 + 1], j2 = idx[r * 3 + 2];
    const float w0 = w[r * 3 + 0], w1 = w[r * 3 + 1], w2 = w[r * 3 + 2];
    const short8 a0 = *(const short8*)(Ka + ((long)j0 * BDIM + b) * CD + j * 8);
    const short8 a1 = *(const short8*)(Ka + ((long)j1 * BDIM + b) * CD + j * 8);
    const short8 a2 = *(const short8*)(Ka + ((long)j2 * BDIM + b) * CD + j * 8);
    short8 o;
#pragma unroll
    for (int i = 0; i < 8; ++i)
      o[i] = (short)rne_bf16(bf2f((u16)a0[i]) * w0 + bf2f((u16)a1[i]) * w1
                           + bf2f((u16)a2[i]) * w2);
    *(short8*)(IN2 + r * CD + j * 8) = o;
  }
}

// ---------------- L4: kv2-GEMM with Vt2 fold, 1024 blocks
__global__ __launch_bounds__(256) void kv2_kernel(
    const u16* __restrict__ KEY2, const u16* __restrict__ wkv2b,
    u16* __restrict__ KV2, u16* __restrict__ Vt2)
{
  __shared__ __align__(16) u16 SH[16384];
  const int d = blockIdx.x;
  const int n0 = swz_nt(d) * 128;
  if (n0 >= 256)
    gemm_body64<1, 3, 512, 2048>(SH, SH + 8192, KEY2, wkv2b, nullptr, KV2, Vt2,
                                 swz_p(d) * 128, n0);
  else
    gemm_body64<1, 0, 512, 2048>(SH, SH + 8192, KEY2, wkv2b, nullptr, KV2, nullptr,
                                 swz_p(d) * 128, n0);
}

// ------------------------------------------------- proj GEMM, 64x128 tiles, 1D
__global__ __launch_bounds__(256) void gemm_proj64_kernel(
    const u16* __restrict__ A, const u16* __restrict__ W,
    const float* __restrict__ bias, float* __restrict__ out)
{
  __shared__ __align__(16) u16 As[64 * 32];
  __shared__ __align__(16) u16 Ws[128 * 32];
  const int tid = threadIdx.x;
  const int lane = tid & 63, wv = tid >> 6;
  const int d = blockIdx.x;
  const int m0 = swz_p(d) * 64, n0 = swz_nt(d) * 128;

  f32x4 acc[2][4];
#pragma unroll
  for (int mi = 0; mi < 2; ++mi)
#pragma unroll
    for (int ni = 0; ni < 4; ++ni)
#pragma unroll
      for (int r = 0; r < 4; ++r) acc[mi][ni][r] = 0.0f;

  const int ar = tid >> 2, ac = tid & 3;
  const char* gA = (const char*)A + (long)(m0 + ar) * 1024 + ((ac ^ (ar & 3)) << 4);
  const char* gW[2];
#pragma unroll
  for (int s = 0; s < 2; ++s) {
    const int rw = s * 64 + ar;
    gW[s] = (const char*)W + (long)(n0 + rw) * 1024 + ((ac ^ (rw & 3)) << 4);
  }
  const int wr = (wv >> 1) * 32, wc = (wv & 1) * 64;
  const int g = lane >> 4, cl = lane & 15;
  const int gx = (g ^ (cl & 3)) << 4;

  for (int kt = 0; kt < 16; ++kt) {
    GLOAD16(gA, (char*)As + tid * 16); gA += 64;
#pragma unroll
    for (int s = 0; s < 2; ++s) {
      GLOAD16(gW[s], (char*)Ws + (s * 256 + tid) * 16); gW[s] += 64;
    }
    __syncthreads();
    short8 af[2], bf[4];
#pragma unroll
    for (int i = 0; i < 2; ++i)
      af[i] = *(const short8*)((const char*)As + (wr + i * 16 + cl) * 64 + gx);
#pragma unroll
    for (int j = 0; j < 4; ++j)
      bf[j] = *(const short8*)((const char*)Ws + (wc + j * 16 + cl) * 64 + gx);
#pragma unroll
    for (int mi = 0; mi < 2; ++mi)
#pragma unroll
      for (int ni = 0; ni < 4; ++ni)
        acc[mi][ni] = __builtin_amdgcn_mfma_f32_16x16x32_bf16(af[mi], bf[ni], acc[mi][ni], 0, 0, 0);
    __syncthreads();
  }

#pragma unroll
  for (int mi = 0; mi < 2; ++mi)
#pragma unroll
    for (int ni = 0; ni < 4; ++ni)
#pragma unroll
      for (int r = 0; r < 4; ++r) {
        const int gm = m0 + wr + mi * 16 + g * 4 + r;
        const int gn = n0 + wc + ni * 16 + cl;
        out[((long)(gm & 1023) * BDIM + (gm >> 10)) * 512 + gn] = acc[mi][ni][r] + bias[gn];
      }
}

// ---------------------------------------------------------------- attention
// (verbatim R12 — proven) 32x32x16 MFMA flash: 128-q blocks, 4 waves x 32 q,
// sigma-permuted swapped QK^T (pi(r) = r^12 when ((r>>2)^(r>>3))&1), fixed-m
// exp2 softmax, in-lane cvt_pk P-packing, per-S-block QK/PV interleave.
template<int NK>
__device__ __forceinline__ void attn_body32(
    u16* __restrict__ Ks, u16* __restrict__ Vs,
    const u16* __restrict__ Q, const u16* __restrict__ KV,
    const u16* __restrict__ Vt, u16* __restrict__ X,
    const int h, const int sc, const int qt, const int b)
{
  const int tid = threadIdx.x;
  const int lane = tid & 63, wv = tid >> 6;
  const int hi = lane >> 5, ql = lane & 31;

  const u16* qptr = Q + ((size_t)(b * 1024 + qt * 128 + wv * 32 + ql)) * 512
                      + (sc * 4 + h) * 64 + hi * 8;
  short8 qf[4];
#pragma unroll
  for (int t = 0; t < 4; ++t) qf[t] = *(const short8*)(qptr + t * 16);

  f32x16 acc0, acc1;
#pragma unroll
  for (int i = 0; i < 16; ++i) { acc0[i] = 0.0f; acc1[i] = 0.0f; }
  float l = 0.0f;

  const char* kB = (const char*)(KV + (size_t)b * NK * 512 + h * 64);
  const char* vB = (const char*)(Vt + (size_t)((b * 4 + h) * 64) * NK);
  uint32_t koffL[4], voffL[4];
#pragma unroll
  for (int s = 0; s < 4; ++s) {
    const int c = s * 256 + tid;
    { const int key = c >> 3, cp = c & 7;
      koffL[s] = key * 1024 + ((cp ^ (key & 7)) << 4); }
    { const int d = c >> 4, cp = c & 15;
      voffL[s] = d * (NK * 2) + ((cp ^ (d & 15)) << 4); }
  }

  const int sel = ((ql >> 2) ^ (ql >> 3)) & 1;
  const int kpi = ql ^ (sel ? 12 : 0);
  int kaddr[4];
#pragma unroll
  for (int t = 0; t < 4; ++t)
    kaddr[t] = kpi * 128 + (((t * 2 + hi) ^ (kpi & 7)) << 4);
  const int vx = ql & 15;

  constexpr int NT = NK / 128;
#define ISSUE_KV(kt_) { \
  const char* kT_ = kB + (size_t)(kt_) * 131072; \
  const char* vT_ = vB + (size_t)(kt_) * 256; \
  _Pragma("unroll") for (int s_ = 0; s_ < 4; ++s_) { \
    GLOAD16(kT_ + koffL[s_], (char*)Ks + (s_ * 256 + tid) * 16); \
    GLOAD16(vT_ + voffL[s_], (char*)Vs + (s_ * 256 + tid) * 16); } }

  ISSUE_KV(0);

  for (int kt = 0; kt < NT; ++kt) {
    asm volatile("s_waitcnt vmcnt(0)" ::: "memory");
    __builtin_amdgcn_s_barrier();
    __builtin_amdgcn_sched_barrier(0);

#pragma unroll
    for (int blk = 0; blk < 4; ++blk) {
      f32x16 sv;
#pragma unroll
      for (int i = 0; i < 16; ++i) sv[i] = 0.0f;
      __builtin_amdgcn_s_setprio(1);
#pragma unroll
      for (int t = 0; t < 4; ++t) {
        const short8 kf = *(const short8*)((const char*)Ks + blk * 4096 + kaddr[t]);
        sv = __builtin_amdgcn_mfma_f32_32x32x16_bf16(kf, qf[t], sv, 0, 0, 0);
      }
      __builtin_amdgcn_s_setprio(0);
#pragma unroll
      for (int i = 0; i < 16; ++i) {
        sv[i] = __builtin_amdgcn_exp2f(sv[i]);
        l += sv[i];
      }
#pragma unroll
      for (int sh = 0; sh < 2; ++sh) {
        u32x4 pw;
        asm("v_cvt_pk_bf16_f32 %0, %1, %2" : "=v"(pw[0]) : "v"(sv[8*sh+0]), "v"(sv[8*sh+1]));
        asm("v_cvt_pk_bf16_f32 %0, %1, %2" : "=v"(pw[1]) : "v"(sv[8*sh+2]), "v"(sv[8*sh+3]));
        asm("v_cvt_pk_bf16_f32 %0, %1, %2" : "=v"(pw[2]) : "v"(sv[8*sh+4]), "v"(sv[8*sh+5]));
        asm("v_cvt_pk_bf16_f32 %0, %1, %2" : "=v"(pw[3]) : "v"(sv[8*sh+6]), "v"(sv[8*sh+7]));
        const short8 pa = __builtin_bit_cast(short8, pw);
        const int step = blk * 2 + sh;
        const int vchunk = ((step * 2 + hi) ^ vx) << 4;
        __builtin_amdgcn_s_setprio(1);
        {
          const short8 vf0 = *(const short8*)((const char*)Vs + ql * 256 + vchunk);
          acc0 = __builtin_amdgcn_mfma_f32_32x32x16_bf16(pa, vf0, acc0, 0, 0, 0);
          const short8 vf1 = *(const short8*)((const char*)Vs + (32 + ql) * 256 + vchunk);
          acc1 = __builtin_amdgcn_mfma_f32_32x32x16_bf16(pa, vf1, acc1, 0, 0, 0);
        }
        __builtin_amdgcn_s_setprio(0);
      }
    }

    asm volatile("s_waitcnt lgkmcnt(0)" ::: "memory");
    __builtin_amdgcn_sched_barrier(0);
    __builtin_amdgcn_s_barrier();
    if (kt + 1 < NT) { ISSUE_KV(kt + 1); }
  }
#undef ISSUE_KV

  l += __shfl_xor(l, 32);
  const float inv = 1.0f / l;
  const long qbase = (long)b * 1024 + qt * 128 + wv * 32;
#pragma unroll
  for (int i = 0; i < 16; ++i) {
    const int row = (i & 3) + 8 * (i >> 2) + 4 * hi;
    const float ir = __shfl(inv, row);
    const long go = (qbase + row) * 512 + sc * 256 + h * 64 + ql;
    X[go]      = rne_bf16(acc0[i] * ir);
    X[go + 32] = rne_bf16(acc1[i] * ir);
  }
}

__global__ __launch_bounds__(256, 4) void attn_fused32_kernel(
    const u16* __restrict__ Q,
    const u16* __restrict__ KV1, const u16* __restrict__ KV2,
    const u16* __restrict__ Vt1, const u16* __restrict__ Vt2,
    u16* __restrict__ X)
{
  __shared__ __align__(16) u16 Ks[128 * 64];   // 128 keys x 64 d
  __shared__ __align__(16) u16 Vs[64 * 128];   // 64 d x 128 keys
  const int d = blockIdx.x;
  const int qt = (d >> 3) & 7;
  const int grp = (d & 7) | ((d >> 6) << 3);
  const int b = grp & 15, z = grp >> 4;
  if (z < 4) attn_body32<1024>(Ks, Vs, Q, KV1, Vt1, X, z, 0, qt, b);
  else       attn_body32<2048>(Ks, Vs, Q, KV2, Vt2, X, z - 4, 1, qt, b);
}

// ---------------------------------------------------------------- launch
extern "C" void kernel_launch(void* const* d_in, const int* in_sizes, int n_in,
                              void* d_out, int out_size, void* d_ws, size_t ws_size,
                              hipStream_t stream) {
  const float* query   = (const float*)d_in[0];
  const float* key     = (const float*)d_in[1];
  const float* key_pos = (const float*)d_in[2];
  const float* xyz_up  = (const float*)d_in[4];
  const float* Wq      = (const float*)d_in[5];
  const float* Wkv1    = (const float*)d_in[6];
  const float* Wkv2    = (const float*)d_in[7];
  const float* fp_w    = (const float*)d_in[8];
  const float* fp_b    = (const float*)d_in[9];
  const float* proj_w  = (const float*)d_in[10];
  const float* proj_b  = (const float*)d_in[11];

  char* ws = (char*)d_ws;
  const size_t MB = 1024 * 1024;
  u16*  Qa    = (u16*)(ws + 0);          // 16MB bf16 query; later X
  u16*  Ka    = (u16*)(ws + 16 * MB);    // 16MB bf16 key
  u16*  Qb    = (u16*)(ws + 32 * MB);    // 16MB
  u16*  KV1   = (u16*)(ws + 48 * MB);    // 16MB (K half valid)
  u16*  IN2   = (u16*)(ws + 64 * MB);    // 32MB interp; later KV2 (K half)
  u16*  KEY2  = (u16*)(ws + 96 * MB);    // 32MB
  u16*  Vt1   = (u16*)(ws + 128 * MB);   //  8MB
  u16*  Vt2   = (u16*)(ws + 136 * MB);   // 16MB
  u16*  Wq2   = (u16*)(ws + 152 * MB);
  u16*  Wkv12 = (u16*)(ws + 152 * MB + 512 * 1024);
  u16*  proj2 = (u16*)(ws + 153 * MB);
  u16*  fpwb  = (u16*)(ws + 153 * MB + 512 * 1024);
  u16*  wkv2b = (u16*)(ws + 154 * MB);
  int*  idxb  = (int*)(ws + 155 * MB);
  float* wb   = (float*)(ws + 156 * MB);
  u16*  KV2   = IN2;
  u16*  X     = Qa;

  // 1. conversions + 3-NN
  prep_kernel<<<dim3(10880), 256, 0, stream>>>(
      query, Qa, key, Ka, Wq, Wkv1, proj_w, fp_w, Wkv2,
      Wq2, Wkv12, proj2, fpwb, wkv2b, key_pos, xyz_up, idxb, wb);
  // 2. q-GEMM + kv1-GEMM (Vt1 folded) + interp
  qkv1_interp_kernel<<<dim3(9216), 256, 0, stream>>>(
      Qa, Wq2, Qb, Ka, Wkv12, KV1, Vt1, idxb, wb, IN2);
  // 3. key2 = relu(interp @ fp_w^T + b)
  gemm_fp_kernel<<<dim3(1024), 256, 0, stream>>>(IN2, fpwb, fp_b, KEY2);
  // 4. kv2-GEMM (Vt2 folded)
  kv2_kernel<<<dim3(1024), 256, 0, stream>>>(KEY2, wkv2b, KV2, Vt2);
  // 5. fused attention (both scales, R12-proven 32x32 MFMA) -> X
  attn_fused32_kernel<<<dim3(1024), 256, 0, stream>>>(Qb, KV1, KV2, Vt1, Vt2, X);
  // 6. output projection + final transpose
  gemm_proj64_kernel<<<dim3(1024), 256, 0, stream>>>(X, proj2, proj_b, (float*)d_out);
}

// Round 16
// 215.514 us; speedup vs baseline: 1.0322x; 1.0322x over previous
//
#include <hip/hip_runtime.h>
#include <cstdint>
#include <cstddef>

#define CD   512
#define BDIM 16
#define NQ   1024
#define NP   1024
#define NUP  2048

typedef unsigned short u16;
typedef short short8 __attribute__((ext_vector_type(8)));
typedef float f32x4  __attribute__((ext_vector_type(4)));
typedef float f32x16 __attribute__((ext_vector_type(16)));
typedef uint32_t u32x4 __attribute__((ext_vector_type(4)));

#define GLOAD16(g, l) __builtin_amdgcn_global_load_lds( \
    (const __attribute__((address_space(1))) void*)(g), \
    (__attribute__((address_space(3))) void*)(l), 16, 0, 0)

__device__ __forceinline__ u16 rne_bf16(float x) {
  uint32_t u = __float_as_uint(x);
  return (u16)((u + 0x7fffu + ((u >> 16) & 1u)) >> 16);
}
__device__ __forceinline__ float bf2f(u16 v) {
  return __uint_as_float(((uint32_t)v) << 16);
}

// ---------------------------------------------------- prep: conversions + 3-NN
__global__ __launch_bounds__(256) void prep_kernel(
    const float* __restrict__ query, u16* __restrict__ Qa,
    const float* __restrict__ key, u16* __restrict__ Ka,
    const float* __restrict__ Wq, const float* __restrict__ Wkv1,
    const float* __restrict__ projw, const float* __restrict__ fpw,
    const float* __restrict__ wkv2, u16* __restrict__ Wq2,
    u16* __restrict__ Wkv12, u16* __restrict__ proj2,
    u16* __restrict__ fpwb, u16* __restrict__ wkv2b,
    const float* __restrict__ key_pos, const float* __restrict__ xyz_up,
    int* __restrict__ idx_out, float* __restrict__ w_out)
{
  const int bx = blockIdx.x;
  const int tid = threadIdx.x;
  if (bx < 8832) {
    const float* in; u16* out; float scl = 1.0f; long u;
    if (bx < 8192) {
      in = (bx < 4096) ? query : key;
      out = (bx < 4096) ? Qa : Ka;
      u = (long)(bx & 4095) * 256 + tid;
    } else {
      const int job = (bx - 8192) >> 7;
      in  = (job == 0) ? Wq  : (job == 1) ? Wkv1  : (job == 2) ? projw : (job == 3) ? fpw  : wkv2;
      out = (job == 0) ? Wq2 : (job == 1) ? Wkv12 : (job == 2) ? proj2 : (job == 3) ? fpwb : wkv2b;
      if (job == 0) scl = 0.18033688011112042f;   // 0.125 * log2(e)
      u = (long)((bx - 8192) & 127) * 256 + tid;
    }
    const float* ip = in + u * 8;
    float v[8];
    *(float4*)&v[0] = *(const float4*)ip;
    *(float4*)&v[4] = *(const float4*)(ip + 4);
    short8 o;
#pragma unroll
    for (int i = 0; i < 8; ++i) o[i] = (short)rne_bf16(v[i] * scl);
    *(short8*)(out + u * 8) = o;
    return;
  }
  // ---- 3-NN: 16 points x 16 scanners x 64 keys, float4 LDS, shfl merge
  __shared__ __align__(16) float4 kp4[NP];
  const int kb = bx - 8832;
  const int b = kb >> 7;
  const int n0 = (kb & 127) * 16;
  const float* kpb = key_pos + (long)b * NP * 3;
#pragma unroll
  for (int s = 0; s < 4; ++s) {
    const int t = s * 256 + tid;
    kp4[t] = make_float4(kpb[t * 3], kpb[t * 3 + 1], kpb[t * 3 + 2], 0.0f);
  }
  __syncthreads();
  const int sc = tid & 15, pt = tid >> 4;
  const int n = n0 + pt;
  const float ux = xyz_up[(b * NUP + n) * 3 + 0];
  const float uy = xyz_up[(b * NUP + n) * 3 + 1];
  const float uz = xyz_up[(b * NUP + n) * 3 + 2];
  float e0 = 3.4e38f, e1 = 3.4e38f, e2 = 3.4e38f;
  int j0 = 0, j1 = 0, j2 = 0;
  for (int it = 0; it < 64; ++it) {
    const int j = it * 16 + sc;
    const float4 kv = kp4[j];
    const float dx = ux - kv.x, dy = uy - kv.y, dz = uz - kv.z;
    const float dd = dx * dx + dy * dy + dz * dz;
    if (dd < e2) {
      if (dd < e1) {
        e2 = e1; j2 = j1;
        if (dd < e0) { e1 = e0; j1 = j0; e0 = dd; j0 = j; }
        else         { e1 = dd; j1 = j; }
      } else { e2 = dd; j2 = j; }
    }
  }
#pragma unroll
  for (int ms = 1; ms <= 8; ms <<= 1) {
    const float pd0 = __shfl_xor(e0, ms), pd1 = __shfl_xor(e1, ms), pd2 = __shfl_xor(e2, ms);
    const int   pi0 = __shfl_xor(j0, ms), pi1 = __shfl_xor(j1, ms), pi2 = __shfl_xor(j2, ms);
    float cd[3] = {pd0, pd1, pd2};
    int   ci[3] = {pi0, pi1, pi2};
#pragma unroll
    for (int t = 0; t < 3; ++t) {
      const float dd = cd[t]; const int jj = ci[t];
      if (dd < e2 || (dd == e2 && jj < j2)) {
        if (dd < e1 || (dd == e1 && jj < j1)) {
          e2 = e1; j2 = j1;
          if (dd < e0 || (dd == e0 && jj < j0)) { e1 = e0; j1 = j0; e0 = dd; j0 = jj; }
          else                                  { e1 = dd; j1 = jj; }
        } else { e2 = dd; j2 = jj; }
      }
    }
  }
  if (sc == 0) {
    const float w0 = 1.0f / (e0 + 1e-8f);
    const float w1 = 1.0f / (e1 + 1e-8f);
    const float w2 = 1.0f / (e2 + 1e-8f);
    const float inv = 1.0f / ((w0 + w1) + w2);
    const long r = (long)b * NUP + n;
    idx_out[r * 3 + 0] = j0; idx_out[r * 3 + 1] = j1; idx_out[r * 3 + 2] = j2;
    w_out[r * 3 + 0] = w0 * inv; w_out[r * 3 + 1] = w1 * inv; w_out[r * 3 + 2] = w2 * inv;
  }
}

// ------------------------------------------------- interp (bf16 in/out)
__global__ __launch_bounds__(256) void interp_bf16_kernel(
    const u16* __restrict__ Ka, const int* __restrict__ idx,
    const float* __restrict__ w, u16* __restrict__ out)
{
  const int t = threadIdx.x;
  const long r = (long)blockIdx.x * 4 + (t >> 6);
  const int j = t & 63;
  const int b = (int)(r >> 11);
  const int j0 = idx[r * 3 + 0], j1 = idx[r * 3 + 1], j2 = idx[r * 3 + 2];
  const float w0 = w[r * 3 + 0], w1 = w[r * 3 + 1], w2 = w[r * 3 + 2];
  const short8 a0 = *(const short8*)(Ka + ((long)j0 * BDIM + b) * CD + j * 8);
  const short8 a1 = *(const short8*)(Ka + ((long)j1 * BDIM + b) * CD + j * 8);
  const short8 a2 = *(const short8*)(Ka + ((long)j2 * BDIM + b) * CD + j * 8);
  short8 o;
#pragma unroll
  for (int i = 0; i < 8; ++i)
    o[i] = (short)rne_bf16(bf2f((u16)a0[i]) * w0 + bf2f((u16)a1[i]) * w1
                         + bf2f((u16)a2[i]) * w2);
  *(short8*)(out + r * CD + j * 8) = o;
}

// ---------------------------------------------------------------- GEMM BK=64
// OMODE 0: bf16 (M,512); 1: +bias+relu; 2: fp32 +bias transposed rows;
// OMODE 3: V-transpose epilogue -> Vt[((b*4+h)*64+d)*NKT + point], no KV write.
template<int AMODE, int OMODE, int KE, int NKT>
__device__ __forceinline__ void gemm_body64(
    u16* __restrict__ As, u16* __restrict__ Ws,
    const u16* __restrict__ A, const u16* __restrict__ W,
    const float* __restrict__ bias, void* __restrict__ outv,
    u16* __restrict__ Vt, const int m0, const int n0)
{
  const int tid = threadIdx.x;
  const int lane = tid & 63, wv = tid >> 6;
  const int rch = tid & 7;

  f32x4 acc[4][4];
#pragma unroll
  for (int mi = 0; mi < 4; ++mi)
#pragma unroll
    for (int ni = 0; ni < 4; ++ni)
#pragma unroll
      for (int r = 0; r < 4; ++r) acc[mi][ni][r] = 0.0f;

  const long rowb = (long)KE * 2;
  const char* gA[4]; const char* gW[4];
#pragma unroll
  for (int s = 0; s < 4; ++s) {
    const int row = s * 32 + (tid >> 3);
    const int gm = m0 + row;
    const long arow = (AMODE == 0) ? (long)gm : (long)(gm & 15) * 2048 + (gm >> 4);
    const int kb0 = (rch ^ (row & 7)) << 4;
    gA[s] = (const char*)A + arow * rowb + kb0;
    gW[s] = (const char*)W + (long)(n0 + row) * rowb + kb0;
  }
  const int wr = (wv >> 1) * 64, wc = (wv & 1) * 64;
  const int g = lane >> 4, cl = lane & 15;

  for (int kt = 0; kt < KE / 64; ++kt) {
#pragma unroll
    for (int s = 0; s < 4; ++s) {
      GLOAD16(gA[s], (char*)As + (s * 256 + tid) * 16);
      GLOAD16(gW[s], (char*)Ws + (s * 256 + tid) * 16);
      gA[s] += 128; gW[s] += 128;
    }
    __syncthreads();
#pragma unroll
    for (int kb = 0; kb < 2; ++kb) {
      short8 af[4], bf[4];
#pragma unroll
      for (int i = 0; i < 4; ++i) {
        const int ra = wr + i * 16 + cl;
        af[i] = *(const short8*)((const char*)As + ra * 128
                 + ((kb * 64 + g * 16) ^ ((ra & 7) << 4)));
        const int rb = wc + i * 16 + cl;
        bf[i] = *(const short8*)((const char*)Ws + rb * 128
                 + ((kb * 64 + g * 16) ^ ((rb & 7) << 4)));
      }
#pragma unroll
      for (int mi = 0; mi < 4; ++mi)
#pragma unroll
        for (int ni = 0; ni < 4; ++ni)
          acc[mi][ni] = __builtin_amdgcn_mfma_f32_16x16x32_bf16(af[mi], bf[ni], acc[mi][ni], 0, 0, 0);
    }
    __syncthreads();
  }

  if constexpr (OMODE == 3) {
    u16* T = As;
#pragma unroll
    for (int ni = 0; ni < 4; ++ni) {
      const int n = wc + ni * 16 + cl;
      const int swz = (n & 15) << 4;
      const int rb2 = n * 256;
#pragma unroll
      for (int mi = 0; mi < 4; ++mi) {
        uint32_t lo, hi;
        asm("v_cvt_pk_bf16_f32 %0, %1, %2" : "=v"(lo) : "v"(acc[mi][ni][0]), "v"(acc[mi][ni][1]));
        asm("v_cvt_pk_bf16_f32 %0, %1, %2" : "=v"(hi) : "v"(acc[mi][ni][2]), "v"(acc[mi][ni][3]));
        const int m2 = 2 * (wr + mi * 16 + g * 4);
        uint2 pk; pk.x = lo; pk.y = hi;
        *(uint2*)((char*)T + rb2 + (m2 ^ swz)) = pk;
      }
    }
    __syncthreads();
    const int nl = tid >> 1, mh = tid & 1;
    const int v = (n0 - 256) + nl;
    const int hh = v >> 6, dd = v & 63;
    const int bq = m0 / NKT;
    const int p0 = (m0 & (NKT - 1)) + mh * 64;
    u16* dst = Vt + ((size_t)((bq * 4 + hh) * 64 + dd)) * NKT + p0;
    const int swz = (nl & 15) << 4;
#pragma unroll
    for (int j = 0; j < 8; ++j) {
      const int m2 = mh * 128 + j * 16;
      const short8 val = *(const short8*)((const char*)T + nl * 256 + (m2 ^ swz));
      *(short8*)(dst + j * 8) = val;
    }
    return;
  } else {
#pragma unroll
    for (int mi = 0; mi < 4; ++mi)
#pragma unroll
      for (int ni = 0; ni < 4; ++ni)
#pragma unroll
        for (int r = 0; r < 4; ++r) {
          const int gm = m0 + wr + mi * 16 + g * 4 + r;
          const int gn = n0 + wc + ni * 16 + cl;
          float vv = acc[mi][ni][r];
          if (OMODE == 0) {
            ((u16*)outv)[(long)gm * 512 + gn] = rne_bf16(vv);
          } else if (OMODE == 1) {
            vv = fmaxf(vv + bias[gn], 0.0f);
            ((u16*)outv)[(long)gm * 512 + gn] = rne_bf16(vv);
          } else {
            vv += bias[gn];
            ((float*)outv)[((long)(gm & 1023) * BDIM + (gm >> 10)) * 512 + gn] = vv;
          }
        }
  }
}

// panel-XCD swizzle: 4 N-tiles sharing one A-panel land on one XCD.
__device__ __forceinline__ int swz_p(int d)  { return (d & 7) | ((d >> 5) << 3); }
__device__ __forceinline__ int swz_nt(int d) { return (d >> 3) & 3; }

// ---------------- L3: q-GEMM (512) + kv1-GEMM w/ Vt1 fold (512) + fp-GEMM (1024)
// All three jobs share the same gemm_body64 resource profile -> homogeneous
// merge, fp blocks backfill while q/kv1 run (fp depends only on interp).
__global__ __launch_bounds__(256) void gemm_mega_kernel(
    const u16* __restrict__ Qa, const u16* __restrict__ Wq2, u16* __restrict__ Qb,
    const u16* __restrict__ Ka, const u16* __restrict__ Wkv12,
    u16* __restrict__ KV1, u16* __restrict__ Vt1,
    const u16* __restrict__ IN2, const u16* __restrict__ fpwb,
    const float* __restrict__ fp_b, u16* __restrict__ KEY2)
{
  __shared__ __align__(16) u16 SH[16384];
  const int bid = blockIdx.x;
  if (bid < 512) {
    gemm_body64<0, 0, 512, 1024>(SH, SH + 8192, Qa, Wq2, nullptr, Qb, nullptr,
                                 swz_p(bid) * 128, swz_nt(bid) * 128);
  } else if (bid < 1024) {
    const int t = bid - 512;
    const int n0 = swz_nt(t) * 128;
    if (n0 >= 256)
      gemm_body64<0, 3, 512, 1024>(SH, SH + 8192, Ka, Wkv12, nullptr, KV1, Vt1,
                                   swz_p(t) * 128, n0);
    else
      gemm_body64<0, 0, 512, 1024>(SH, SH + 8192, Ka, Wkv12, nullptr, KV1, nullptr,
                                   swz_p(t) * 128, n0);
  } else {
    const int t = bid - 1024;
    gemm_body64<0, 1, 512, 1024>(SH, SH + 8192, IN2, fpwb, fp_b, KEY2, nullptr,
                                 swz_p(t) * 128, swz_nt(t) * 128);
  }
}

// ---------------- L4: kv2-GEMM with Vt2 fold, 1024 blocks
__global__ __launch_bounds__(256) void kv2_kernel(
    const u16* __restrict__ KEY2, const u16* __restrict__ wkv2b,
    u16* __restrict__ KV2, u16* __restrict__ Vt2)
{
  __shared__ __align__(16) u16 SH[16384];
  const int d = blockIdx.x;
  const int n0 = swz_nt(d) * 128;
  if (n0 >= 256)
    gemm_body64<1, 3, 512, 2048>(SH, SH + 8192, KEY2, wkv2b, nullptr, KV2, Vt2,
                                 swz_p(d) * 128, n0);
  else
    gemm_body64<1, 0, 512, 2048>(SH, SH + 8192, KEY2, wkv2b, nullptr, KV2, nullptr,
                                 swz_p(d) * 128, n0);
}

// ------------------------------------------------- proj GEMM, 64x128 tiles, 1D
__global__ __launch_bounds__(256) void gemm_proj64_kernel(
    const u16* __restrict__ A, const u16* __restrict__ W,
    const float* __restrict__ bias, float* __restrict__ out)
{
  __shared__ __align__(16) u16 As[64 * 32];
  __shared__ __align__(16) u16 Ws[128 * 32];
  const int tid = threadIdx.x;
  const int lane = tid & 63, wv = tid >> 6;
  const int d = blockIdx.x;
  const int m0 = swz_p(d) * 64, n0 = swz_nt(d) * 128;

  f32x4 acc[2][4];
#pragma unroll
  for (int mi = 0; mi < 2; ++mi)
#pragma unroll
    for (int ni = 0; ni < 4; ++ni)
#pragma unroll
      for (int r = 0; r < 4; ++r) acc[mi][ni][r] = 0.0f;

  const int ar = tid >> 2, ac = tid & 3;
  const char* gA = (const char*)A + (long)(m0 + ar) * 1024 + ((ac ^ (ar & 3)) << 4);
  const char* gW[2];
#pragma unroll
  for (int s = 0; s < 2; ++s) {
    const int rw = s * 64 + ar;
    gW[s] = (const char*)W + (long)(n0 + rw) * 1024 + ((ac ^ (rw & 3)) << 4);
  }
  const int wr = (wv >> 1) * 32, wc = (wv & 1) * 64;
  const int g = lane >> 4, cl = lane & 15;
  const int gx = (g ^ (cl & 3)) << 4;

  for (int kt = 0; kt < 16; ++kt) {
    GLOAD16(gA, (char*)As + tid * 16); gA += 64;
#pragma unroll
    for (int s = 0; s < 2; ++s) {
      GLOAD16(gW[s], (char*)Ws + (s * 256 + tid) * 16); gW[s] += 64;
    }
    __syncthreads();
    short8 af[2], bf[4];
#pragma unroll
    for (int i = 0; i < 2; ++i)
      af[i] = *(const short8*)((const char*)As + (wr + i * 16 + cl) * 64 + gx);
#pragma unroll
    for (int j = 0; j < 4; ++j)
      bf[j] = *(const short8*)((const char*)Ws + (wc + j * 16 + cl) * 64 + gx);
#pragma unroll
    for (int mi = 0; mi < 2; ++mi)
#pragma unroll
      for (int ni = 0; ni < 4; ++ni)
        acc[mi][ni] = __builtin_amdgcn_mfma_f32_16x16x32_bf16(af[mi], bf[ni], acc[mi][ni], 0, 0, 0);
    __syncthreads();
  }

#pragma unroll
  for (int mi = 0; mi < 2; ++mi)
#pragma unroll
    for (int ni = 0; ni < 4; ++ni)
#pragma unroll
      for (int r = 0; r < 4; ++r) {
        const int gm = m0 + wr + mi * 16 + g * 4 + r;
        const int gn = n0 + wc + ni * 16 + cl;
        out[((long)(gm & 1023) * BDIM + (gm >> 10)) * 512 + gn] = acc[mi][ni][r] + bias[gn];
      }
}

// ---------------------------------------------------------------- attention
// (verbatim R12/R15 — proven) 32x32x16 MFMA flash: 128-q blocks, 4 waves x 32 q,
// sigma-permuted swapped QK^T (pi(r) = r^12 when ((r>>2)^(r>>3))&1), fixed-m
// exp2 softmax, in-lane cvt_pk P-packing, per-S-block QK/PV interleave.
template<int NK>
__device__ __forceinline__ void attn_body32(
    u16* __restrict__ Ks, u16* __restrict__ Vs,
    const u16* __restrict__ Q, const u16* __restrict__ KV,
    const u16* __restrict__ Vt, u16* __restrict__ X,
    const int h, const int sc, const int qt, const int b)
{
  const int tid = threadIdx.x;
  const int lane = tid & 63, wv = tid >> 6;
  const int hi = lane >> 5, ql = lane & 31;

  const u16* qptr = Q + ((size_t)(b * 1024 + qt * 128 + wv * 32 + ql)) * 512
                      + (sc * 4 + h) * 64 + hi * 8;
  short8 qf[4];
#pragma unroll
  for (int t = 0; t < 4; ++t) qf[t] = *(const short8*)(qptr + t * 16);

  f32x16 acc0, acc1;
#pragma unroll
  for (int i = 0; i < 16; ++i) { acc0[i] = 0.0f; acc1[i] = 0.0f; }
  float l = 0.0f;

  const char* kB = (const char*)(KV + (size_t)b * NK * 512 + h * 64);
  const char* vB = (const char*)(Vt + (size_t)((b * 4 + h) * 64) * NK);
  uint32_t koffL[4], voffL[4];
#pragma unroll
  for (int s = 0; s < 4; ++s) {
    const int c = s * 256 + tid;
    { const int key = c >> 3, cp = c & 7;
      koffL[s] = key * 1024 + ((cp ^ (key & 7)) << 4); }
    { const int d = c >> 4, cp = c & 15;
      voffL[s] = d * (NK * 2) + ((cp ^ (d & 15)) << 4); }
  }

  const int sel = ((ql >> 2) ^ (ql >> 3)) & 1;
  const int kpi = ql ^ (sel ? 12 : 0);
  int kaddr[4];
#pragma unroll
  for (int t = 0; t < 4; ++t)
    kaddr[t] = kpi * 128 + (((t * 2 + hi) ^ (kpi & 7)) << 4);
  const int vx = ql & 15;

  constexpr int NT = NK / 128;
#define ISSUE_KV(kt_) { \
  const char* kT_ = kB + (size_t)(kt_) * 131072; \
  const char* vT_ = vB + (size_t)(kt_) * 256; \
  _Pragma("unroll") for (int s_ = 0; s_ < 4; ++s_) { \
    GLOAD16(kT_ + koffL[s_], (char*)Ks + (s_ * 256 + tid) * 16); \
    GLOAD16(vT_ + voffL[s_], (char*)Vs + (s_ * 256 + tid) * 16); } }

  ISSUE_KV(0);

  for (int kt = 0; kt < NT; ++kt) {
    asm volatile("s_waitcnt vmcnt(0)" ::: "memory");
    __builtin_amdgcn_s_barrier();
    __builtin_amdgcn_sched_barrier(0);

#pragma unroll
    for (int blk = 0; blk < 4; ++blk) {
      f32x16 sv;
#pragma unroll
      for (int i = 0; i < 16; ++i) sv[i] = 0.0f;
      __builtin_amdgcn_s_setprio(1);
#pragma unroll
      for (int t = 0; t < 4; ++t) {
        const short8 kf = *(const short8*)((const char*)Ks + blk * 4096 + kaddr[t]);
        sv = __builtin_amdgcn_mfma_f32_32x32x16_bf16(kf, qf[t], sv, 0, 0, 0);
      }
      __builtin_amdgcn_s_setprio(0);
#pragma unroll
      for (int i = 0; i < 16; ++i) {
        sv[i] = __builtin_amdgcn_exp2f(sv[i]);
        l += sv[i];
      }
#pragma unroll
      for (int sh = 0; sh < 2; ++sh) {
        u32x4 pw;
        asm("v_cvt_pk_bf16_f32 %0, %1, %2" : "=v"(pw[0]) : "v"(sv[8*sh+0]), "v"(sv[8*sh+1]));
        asm("v_cvt_pk_bf16_f32 %0, %1, %2" : "=v"(pw[1]) : "v"(sv[8*sh+2]), "v"(sv[8*sh+3]));
        asm("v_cvt_pk_bf16_f32 %0, %1, %2" : "=v"(pw[2]) : "v"(sv[8*sh+4]), "v"(sv[8*sh+5]));
        asm("v_cvt_pk_bf16_f32 %0, %1, %2" : "=v"(pw[3]) : "v"(sv[8*sh+6]), "v"(sv[8*sh+7]));
        const short8 pa = __builtin_bit_cast(short8, pw);
        const int step = blk * 2 + sh;
        const int vchunk = ((step * 2 + hi) ^ vx) << 4;
        __builtin_amdgcn_s_setprio(1);
        {
          const short8 vf0 = *(const short8*)((const char*)Vs + ql * 256 + vchunk);
          acc0 = __builtin_amdgcn_mfma_f32_32x32x16_bf16(pa, vf0, acc0, 0, 0, 0);
          const short8 vf1 = *(const short8*)((const char*)Vs + (32 + ql) * 256 + vchunk);
          acc1 = __builtin_amdgcn_mfma_f32_32x32x16_bf16(pa, vf1, acc1, 0, 0, 0);
        }
        __builtin_amdgcn_s_setprio(0);
      }
    }

    asm volatile("s_waitcnt lgkmcnt(0)" ::: "memory");
    __builtin_amdgcn_sched_barrier(0);
    __builtin_amdgcn_s_barrier();
    if (kt + 1 < NT) { ISSUE_KV(kt + 1); }
  }
#undef ISSUE_KV

  l += __shfl_xor(l, 32);
  const float inv = 1.0f / l;
  const long qbase = (long)b * 1024 + qt * 128 + wv * 32;
#pragma unroll
  for (int i = 0; i < 16; ++i) {
    const int row = (i & 3) + 8 * (i >> 2) + 4 * hi;
    const float ir = __shfl(inv, row);
    const long go = (qbase + row) * 512 + sc * 256 + h * 64 + ql;
    X[go]      = rne_bf16(acc0[i] * ir);
    X[go + 32] = rne_bf16(acc1[i] * ir);
  }
}

__global__ __launch_bounds__(256, 4) void attn_fused32_kernel(
    const u16* __restrict__ Q,
    const u16* __restrict__ KV1, const u16* __restrict__ KV2,
    const u16* __restrict__ Vt1, const u16* __restrict__ Vt2,
    u16* __restrict__ X)
{
  __shared__ __align__(16) u16 Ks[128 * 64];   // 128 keys x 64 d
  __shared__ __align__(16) u16 Vs[64 * 128];   // 64 d x 128 keys
  const int d = blockIdx.x;
  const int qt = (d >> 3) & 7;
  const int grp = (d & 7) | ((d >> 6) << 3);
  const int b = grp & 15, z = grp >> 4;
  if (z < 4) attn_body32<1024>(Ks, Vs, Q, KV1, Vt1, X, z, 0, qt, b);
  else       attn_body32<2048>(Ks, Vs, Q, KV2, Vt2, X, z - 4, 1, qt, b);
}

// ---------------------------------------------------------------- launch
extern "C" void kernel_launch(void* const* d_in, const int* in_sizes, int n_in,
                              void* d_out, int out_size, void* d_ws, size_t ws_size,
                              hipStream_t stream) {
  const float* query   = (const float*)d_in[0];
  const float* key     = (const float*)d_in[1];
  const float* key_pos = (const float*)d_in[2];
  const float* xyz_up  = (const float*)d_in[4];
  const float* Wq      = (const float*)d_in[5];
  const float* Wkv1    = (const float*)d_in[6];
  const float* Wkv2    = (const float*)d_in[7];
  const float* fp_w    = (const float*)d_in[8];
  const float* fp_b    = (const float*)d_in[9];
  const float* proj_w  = (const float*)d_in[10];
  const float* proj_b  = (const float*)d_in[11];

  char* ws = (char*)d_ws;
  const size_t MB = 1024 * 1024;
  u16*  Qa    = (u16*)(ws + 0);          // 16MB bf16 query; later X
  u16*  Ka    = (u16*)(ws + 16 * MB);    // 16MB bf16 key
  u16*  Qb    = (u16*)(ws + 32 * MB);    // 16MB
  u16*  KV1   = (u16*)(ws + 48 * MB);    // 16MB (K half valid)
  u16*  IN2   = (u16*)(ws + 64 * MB);    // 32MB interp; later KV2 (K half)
  u16*  KEY2  = (u16*)(ws + 96 * MB);    // 32MB
  u16*  Vt1   = (u16*)(ws + 128 * MB);   //  8MB
  u16*  Vt2   = (u16*)(ws + 136 * MB);   // 16MB
  u16*  Wq2   = (u16*)(ws + 152 * MB);
  u16*  Wkv12 = (u16*)(ws + 152 * MB + 512 * 1024);
  u16*  proj2 = (u16*)(ws + 153 * MB);
  u16*  fpwb  = (u16*)(ws + 153 * MB + 512 * 1024);
  u16*  wkv2b = (u16*)(ws + 154 * MB);
  int*  idxb  = (int*)(ws + 155 * MB);
  float* wb   = (float*)(ws + 156 * MB);
  u16*  KV2   = IN2;
  u16*  X     = Qa;

  // 1. conversions + 3-NN
  prep_kernel<<<dim3(10880), 256, 0, stream>>>(
      query, Qa, key, Ka, Wq, Wkv1, proj_w, fp_w, Wkv2,
      Wq2, Wkv12, proj2, fpwb, wkv2b, key_pos, xyz_up, idxb, wb);
  // 2. inverse-distance interpolation (memory-bound, its own launch)
  interp_bf16_kernel<<<dim3(8192), 256, 0, stream>>>(Ka, idxb, wb, IN2);
  // 3. q-GEMM + kv1-GEMM (Vt1 folded) + fp-GEMM (homogeneous merge)
  gemm_mega_kernel<<<dim3(2048), 256, 0, stream>>>(
      Qa, Wq2, Qb, Ka, Wkv12, KV1, Vt1, IN2, fpwb, fp_b, KEY2);
  // 4. kv2-GEMM (Vt2 folded)
  kv2_kernel<<<dim3(1024), 256, 0, stream>>>(KEY2, wkv2b, KV2, Vt2);
  // 5. fused attention (both scales, R12-proven 32x32 MFMA) -> X
  attn_fused32_kernel<<<dim3(1024), 256, 0, stream>>>(Qb, KV1, KV2, Vt1, Vt2, X);
  // 6. output projection + final transpose
  gemm_proj64_kernel<<<dim3(1024), 256, 0, stream>>>(X, proj2, proj_b, (float*)d_out);
}

// Round 17
// 210.844 us; speedup vs baseline: 1.0550x; 1.0221x over previous
//
#include <hip/hip_runtime.h>
#include <cstdint>
#include <cstddef>

#define CD   512
#define BDIM 16
#define NQ   1024
#define NP   1024
#define NUP  2048

typedef unsigned short u16;
typedef short short8 __attribute__((ext_vector_type(8)));
typedef float f32x4  __attribute__((ext_vector_type(4)));
typedef float f32x16 __attribute__((ext_vector_type(16)));
typedef uint32_t u32x4 __attribute__((ext_vector_type(4)));

#define GLOAD16(g, l) __builtin_amdgcn_global_load_lds( \
    (const __attribute__((address_space(1))) void*)(g), \
    (__attribute__((address_space(3))) void*)(l), 16, 0, 0)

__device__ __forceinline__ u16 rne_bf16(float x) {
  uint32_t u = __float_as_uint(x);
  return (u16)((u + 0x7fffu + ((u >> 16) & 1u)) >> 16);
}
__device__ __forceinline__ float bf2f(u16 v) {
  return __uint_as_float(((uint32_t)v) << 16);
}

// ---------------------------------------------------- prep: conversions + 3-NN
__global__ __launch_bounds__(256) void prep_kernel(
    const float* __restrict__ query, u16* __restrict__ Qa,
    const float* __restrict__ key, u16* __restrict__ Ka,
    const float* __restrict__ Wq, const float* __restrict__ Wkv1,
    const float* __restrict__ projw, const float* __restrict__ fpw,
    const float* __restrict__ wkv2, u16* __restrict__ Wq2,
    u16* __restrict__ Wkv12, u16* __restrict__ proj2,
    u16* __restrict__ fpwb, u16* __restrict__ wkv2b,
    const float* __restrict__ key_pos, const float* __restrict__ xyz_up,
    int* __restrict__ idx_out, float* __restrict__ w_out)
{
  const int bx = blockIdx.x;
  const int tid = threadIdx.x;
  if (bx < 8832) {
    const float* in; u16* out; float scl = 1.0f; long u;
    if (bx < 8192) {
      in = (bx < 4096) ? query : key;
      out = (bx < 4096) ? Qa : Ka;
      u = (long)(bx & 4095) * 256 + tid;
    } else {
      const int job = (bx - 8192) >> 7;
      in  = (job == 0) ? Wq  : (job == 1) ? Wkv1  : (job == 2) ? projw : (job == 3) ? fpw  : wkv2;
      out = (job == 0) ? Wq2 : (job == 1) ? Wkv12 : (job == 2) ? proj2 : (job == 3) ? fpwb : wkv2b;
      if (job == 0) scl = 0.18033688011112042f;   // 0.125 * log2(e)
      u = (long)((bx - 8192) & 127) * 256 + tid;
    }
    const float* ip = in + u * 8;
    float v[8];
    *(float4*)&v[0] = *(const float4*)ip;
    *(float4*)&v[4] = *(const float4*)(ip + 4);
    short8 o;
#pragma unroll
    for (int i = 0; i < 8; ++i) o[i] = (short)rne_bf16(v[i] * scl);
    *(short8*)(out + u * 8) = o;
    return;
  }
  // ---- 3-NN: 16 points x 16 scanners x 64 keys, float4 LDS, shfl merge
  __shared__ __align__(16) float4 kp4[NP];
  const int kb = bx - 8832;
  const int b = kb >> 7;
  const int n0 = (kb & 127) * 16;
  const float* kpb = key_pos + (long)b * NP * 3;
#pragma unroll
  for (int s = 0; s < 4; ++s) {
    const int t = s * 256 + tid;
    kp4[t] = make_float4(kpb[t * 3], kpb[t * 3 + 1], kpb[t * 3 + 2], 0.0f);
  }
  __syncthreads();
  const int sc = tid & 15, pt = tid >> 4;
  const int n = n0 + pt;
  const float ux = xyz_up[(b * NUP + n) * 3 + 0];
  const float uy = xyz_up[(b * NUP + n) * 3 + 1];
  const float uz = xyz_up[(b * NUP + n) * 3 + 2];
  float e0 = 3.4e38f, e1 = 3.4e38f, e2 = 3.4e38f;
  int j0 = 0, j1 = 0, j2 = 0;
  for (int it = 0; it < 64; ++it) {
    const int j = it * 16 + sc;
    const float4 kv = kp4[j];
    const float dx = ux - kv.x, dy = uy - kv.y, dz = uz - kv.z;
    const float dd = dx * dx + dy * dy + dz * dz;
    if (dd < e2) {
      if (dd < e1) {
        e2 = e1; j2 = j1;
        if (dd < e0) { e1 = e0; j1 = j0; e0 = dd; j0 = j; }
        else         { e1 = dd; j1 = j; }
      } else { e2 = dd; j2 = j; }
    }
  }
#pragma unroll
  for (int ms = 1; ms <= 8; ms <<= 1) {
    const float pd0 = __shfl_xor(e0, ms), pd1 = __shfl_xor(e1, ms), pd2 = __shfl_xor(e2, ms);
    const int   pi0 = __shfl_xor(j0, ms), pi1 = __shfl_xor(j1, ms), pi2 = __shfl_xor(j2, ms);
    float cd[3] = {pd0, pd1, pd2};
    int   ci[3] = {pi0, pi1, pi2};
#pragma unroll
    for (int t = 0; t < 3; ++t) {
      const float dd = cd[t]; const int jj = ci[t];
      if (dd < e2 || (dd == e2 && jj < j2)) {
        if (dd < e1 || (dd == e1 && jj < j1)) {
          e2 = e1; j2 = j1;
          if (dd < e0 || (dd == e0 && jj < j0)) { e1 = e0; j1 = j0; e0 = dd; j0 = jj; }
          else                                  { e1 = dd; j1 = jj; }
        } else { e2 = dd; j2 = jj; }
      }
    }
  }
  if (sc == 0) {
    const float w0 = 1.0f / (e0 + 1e-8f);
    const float w1 = 1.0f / (e1 + 1e-8f);
    const float w2 = 1.0f / (e2 + 1e-8f);
    const float inv = 1.0f / ((w0 + w1) + w2);
    const long r = (long)b * NUP + n;
    idx_out[r * 3 + 0] = j0; idx_out[r * 3 + 1] = j1; idx_out[r * 3 + 2] = j2;
    w_out[r * 3 + 0] = w0 * inv; w_out[r * 3 + 1] = w1 * inv; w_out[r * 3 + 2] = w2 * inv;
  }
}

// ------------------------------------------------- interp (bf16 in/out)
__global__ __launch_bounds__(256) void interp_bf16_kernel(
    const u16* __restrict__ Ka, const int* __restrict__ idx,
    const float* __restrict__ w, u16* __restrict__ out)
{
  const int t = threadIdx.x;
  const long r = (long)blockIdx.x * 4 + (t >> 6);
  const int j = t & 63;
  const int b = (int)(r >> 11);
  const int j0 = idx[r * 3 + 0], j1 = idx[r * 3 + 1], j2 = idx[r * 3 + 2];
  const float w0 = w[r * 3 + 0], w1 = w[r * 3 + 1], w2 = w[r * 3 + 2];
  const short8 a0 = *(const short8*)(Ka + ((long)j0 * BDIM + b) * CD + j * 8);
  const short8 a1 = *(const short8*)(Ka + ((long)j1 * BDIM + b) * CD + j * 8);
  const short8 a2 = *(const short8*)(Ka + ((long)j2 * BDIM + b) * CD + j * 8);
  short8 o;
#pragma unroll
  for (int i = 0; i < 8; ++i)
    o[i] = (short)rne_bf16(bf2f((u16)a0[i]) * w0 + bf2f((u16)a1[i]) * w1
                         + bf2f((u16)a2[i]) * w2);
  *(short8*)(out + r * CD + j * 8) = o;
}

// ---------------------------------------------------------------- GEMM BK=64
// OMODE 0: bf16 (M,512); 1: +bias+relu; 2: fp32 +bias transposed rows;
// OMODE 3: V-transpose epilogue -> Vt[((b*4+h)*64+d)*NKT + point], no KV write.
template<int AMODE, int OMODE, int KE, int NKT>
__device__ __forceinline__ void gemm_body64(
    u16* __restrict__ As, u16* __restrict__ Ws,
    const u16* __restrict__ A, const u16* __restrict__ W,
    const float* __restrict__ bias, void* __restrict__ outv,
    u16* __restrict__ Vt, const int m0, const int n0)
{
  const int tid = threadIdx.x;
  const int lane = tid & 63, wv = tid >> 6;
  const int rch = tid & 7;

  f32x4 acc[4][4];
#pragma unroll
  for (int mi = 0; mi < 4; ++mi)
#pragma unroll
    for (int ni = 0; ni < 4; ++ni)
#pragma unroll
      for (int r = 0; r < 4; ++r) acc[mi][ni][r] = 0.0f;

  const long rowb = (long)KE * 2;
  const char* gA[4]; const char* gW[4];
#pragma unroll
  for (int s = 0; s < 4; ++s) {
    const int row = s * 32 + (tid >> 3);
    const int gm = m0 + row;
    const long arow = (AMODE == 0) ? (long)gm : (long)(gm & 15) * 2048 + (gm >> 4);
    const int kb0 = (rch ^ (row & 7)) << 4;
    gA[s] = (const char*)A + arow * rowb + kb0;
    gW[s] = (const char*)W + (long)(n0 + row) * rowb + kb0;
  }
  const int wr = (wv >> 1) * 64, wc = (wv & 1) * 64;
  const int g = lane >> 4, cl = lane & 15;

  for (int kt = 0; kt < KE / 64; ++kt) {
#pragma unroll
    for (int s = 0; s < 4; ++s) {
      GLOAD16(gA[s], (char*)As + (s * 256 + tid) * 16);
      GLOAD16(gW[s], (char*)Ws + (s * 256 + tid) * 16);
      gA[s] += 128; gW[s] += 128;
    }
    __syncthreads();
#pragma unroll
    for (int kb = 0; kb < 2; ++kb) {
      short8 af[4], bf[4];
#pragma unroll
      for (int i = 0; i < 4; ++i) {
        const int ra = wr + i * 16 + cl;
        af[i] = *(const short8*)((const char*)As + ra * 128
                 + ((kb * 64 + g * 16) ^ ((ra & 7) << 4)));
        const int rb = wc + i * 16 + cl;
        bf[i] = *(const short8*)((const char*)Ws + rb * 128
                 + ((kb * 64 + g * 16) ^ ((rb & 7) << 4)));
      }
#pragma unroll
      for (int mi = 0; mi < 4; ++mi)
#pragma unroll
        for (int ni = 0; ni < 4; ++ni)
          acc[mi][ni] = __builtin_amdgcn_mfma_f32_16x16x32_bf16(af[mi], bf[ni], acc[mi][ni], 0, 0, 0);
    }
    __syncthreads();
  }

  if constexpr (OMODE == 3) {
    u16* T = As;
#pragma unroll
    for (int ni = 0; ni < 4; ++ni) {
      const int n = wc + ni * 16 + cl;
      const int swz = (n & 15) << 4;
      const int rb2 = n * 256;
#pragma unroll
      for (int mi = 0; mi < 4; ++mi) {
        uint32_t lo, hi;
        asm("v_cvt_pk_bf16_f32 %0, %1, %2" : "=v"(lo) : "v"(acc[mi][ni][0]), "v"(acc[mi][ni][1]));
        asm("v_cvt_pk_bf16_f32 %0, %1, %2" : "=v"(hi) : "v"(acc[mi][ni][2]), "v"(acc[mi][ni][3]));
        const int m2 = 2 * (wr + mi * 16 + g * 4);
        uint2 pk; pk.x = lo; pk.y = hi;
        *(uint2*)((char*)T + rb2 + (m2 ^ swz)) = pk;
      }
    }
    __syncthreads();
    const int nl = tid >> 1, mh = tid & 1;
    const int v = (n0 - 256) + nl;
    const int hh = v >> 6, dd = v & 63;
    const int bq = m0 / NKT;
    const int p0 = (m0 & (NKT - 1)) + mh * 64;
    u16* dst = Vt + ((size_t)((bq * 4 + hh) * 64 + dd)) * NKT + p0;
    const int swz = (nl & 15) << 4;
#pragma unroll
    for (int j = 0; j < 8; ++j) {
      const int m2 = mh * 128 + j * 16;
      const short8 val = *(const short8*)((const char*)T + nl * 256 + (m2 ^ swz));
      *(short8*)(dst + j * 8) = val;
    }
    return;
  } else {
#pragma unroll
    for (int mi = 0; mi < 4; ++mi)
#pragma unroll
      for (int ni = 0; ni < 4; ++ni)
#pragma unroll
        for (int r = 0; r < 4; ++r) {
          const int gm = m0 + wr + mi * 16 + g * 4 + r;
          const int gn = n0 + wc + ni * 16 + cl;
          float vv = acc[mi][ni][r];
          if (OMODE == 0) {
            ((u16*)outv)[(long)gm * 512 + gn] = rne_bf16(vv);
          } else if (OMODE == 1) {
            vv = fmaxf(vv + bias[gn], 0.0f);
            ((u16*)outv)[(long)gm * 512 + gn] = rne_bf16(vv);
          } else {
            vv += bias[gn];
            ((float*)outv)[((long)(gm & 1023) * BDIM + (gm >> 10)) * 512 + gn] = vv;
          }
        }
  }
}

// panel-XCD swizzle: 4 N-tiles sharing one A-panel land on one XCD.
__device__ __forceinline__ int swz_p(int d)  { return (d & 7) | ((d >> 5) << 3); }
__device__ __forceinline__ int swz_nt(int d) { return (d >> 3) & 3; }

// ---------------- L3: q-GEMM (512) + kv1-GEMM w/ Vt1 fold (512) + fp-GEMM (1024)
__global__ __launch_bounds__(256) void gemm_mega_kernel(
    const u16* __restrict__ Qa, const u16* __restrict__ Wq2, u16* __restrict__ Qb,
    const u16* __restrict__ Ka, const u16* __restrict__ Wkv12,
    u16* __restrict__ KV1, u16* __restrict__ Vt1,
    const u16* __restrict__ IN2, const u16* __restrict__ fpwb,
    const float* __restrict__ fp_b, u16* __restrict__ KEY2)
{
  __shared__ __align__(16) u16 SH[16384];
  const int bid = blockIdx.x;
  if (bid < 512) {
    gemm_body64<0, 0, 512, 1024>(SH, SH + 8192, Qa, Wq2, nullptr, Qb, nullptr,
                                 swz_p(bid) * 128, swz_nt(bid) * 128);
  } else if (bid < 1024) {
    const int t = bid - 512;
    const int n0 = swz_nt(t) * 128;
    if (n0 >= 256)
      gemm_body64<0, 3, 512, 1024>(SH, SH + 8192, Ka, Wkv12, nullptr, KV1, Vt1,
                                   swz_p(t) * 128, n0);
    else
      gemm_body64<0, 0, 512, 1024>(SH, SH + 8192, Ka, Wkv12, nullptr, KV1, nullptr,
                                   swz_p(t) * 128, n0);
  } else {
    const int t = bid - 1024;
    gemm_body64<0, 1, 512, 1024>(SH, SH + 8192, IN2, fpwb, fp_b, KEY2, nullptr,
                                 swz_p(t) * 128, swz_nt(t) * 128);
  }
}

// ---------------- L4: kv2-GEMM with Vt2 fold, 1024 blocks
__global__ __launch_bounds__(256) void kv2_kernel(
    const u16* __restrict__ KEY2, const u16* __restrict__ wkv2b,
    u16* __restrict__ KV2, u16* __restrict__ Vt2)
{
  __shared__ __align__(16) u16 SH[16384];
  const int d = blockIdx.x;
  const int n0 = swz_nt(d) * 128;
  if (n0 >= 256)
    gemm_body64<1, 3, 512, 2048>(SH, SH + 8192, KEY2, wkv2b, nullptr, KV2, Vt2,
                                 swz_p(d) * 128, n0);
  else
    gemm_body64<1, 0, 512, 2048>(SH, SH + 8192, KEY2, wkv2b, nullptr, KV2, nullptr,
                                 swz_p(d) * 128, n0);
}

// ------------------------------------------------- proj GEMM, 64x128 tiles, 1D
__global__ __launch_bounds__(256) void gemm_proj64_kernel(
    const u16* __restrict__ A, const u16* __restrict__ W,
    const float* __restrict__ bias, float* __restrict__ out)
{
  __shared__ __align__(16) u16 As[64 * 32];
  __shared__ __align__(16) u16 Ws[128 * 32];
  const int tid = threadIdx.x;
  const int lane = tid & 63, wv = tid >> 6;
  const int d = blockIdx.x;
  const int m0 = swz_p(d) * 64, n0 = swz_nt(d) * 128;

  f32x4 acc[2][4];
#pragma unroll
  for (int mi = 0; mi < 2; ++mi)
#pragma unroll
    for (int ni = 0; ni < 4; ++ni)
#pragma unroll
      for (int r = 0; r < 4; ++r) acc[mi][ni][r] = 0.0f;

  const int ar = tid >> 2, ac = tid & 3;
  const char* gA = (const char*)A + (long)(m0 + ar) * 1024 + ((ac ^ (ar & 3)) << 4);
  const char* gW[2];
#pragma unroll
  for (int s = 0; s < 2; ++s) {
    const int rw = s * 64 + ar;
    gW[s] = (const char*)W + (long)(n0 + rw) * 1024 + ((ac ^ (rw & 3)) << 4);
  }
  const int wr = (wv >> 1) * 32, wc = (wv & 1) * 64;
  const int g = lane >> 4, cl = lane & 15;
  const int gx = (g ^ (cl & 3)) << 4;

  for (int kt = 0; kt < 16; ++kt) {
    GLOAD16(gA, (char*)As + tid * 16); gA += 64;
#pragma unroll
    for (int s = 0; s < 2; ++s) {
      GLOAD16(gW[s], (char*)Ws + (s * 256 + tid) * 16); gW[s] += 64;
    }
    __syncthreads();
    short8 af[2], bf[4];
#pragma unroll
    for (int i = 0; i < 2; ++i)
      af[i] = *(const short8*)((const char*)As + (wr + i * 16 + cl) * 64 + gx);
#pragma unroll
    for (int j = 0; j < 4; ++j)
      bf[j] = *(const short8*)((const char*)Ws + (wc + j * 16 + cl) * 64 + gx);
#pragma unroll
    for (int mi = 0; mi < 2; ++mi)
#pragma unroll
      for (int ni = 0; ni < 4; ++ni)
        acc[mi][ni] = __builtin_amdgcn_mfma_f32_16x16x32_bf16(af[mi], bf[ni], acc[mi][ni], 0, 0, 0);
    __syncthreads();
  }

#pragma unroll
  for (int mi = 0; mi < 2; ++mi)
#pragma unroll
    for (int ni = 0; ni < 4; ++ni)
#pragma unroll
      for (int r = 0; r < 4; ++r) {
        const int gm = m0 + wr + mi * 16 + g * 4 + r;
        const int gn = n0 + wc + ni * 16 + cl;
        out[((long)(gm & 1023) * BDIM + (gm >> 10)) * 512 + gn] = acc[mi][ni][r] + bias[gn];
      }
}

// ---------------------------------------------------------------- attention
// (body verbatim R12/R15/R16 — proven) 32x32x16 MFMA flash, 128-q per call,
// sigma-permuted swapped QK^T, fixed-m exp2 softmax, in-lane cvt_pk P-packing.
template<int NK>
__device__ __forceinline__ void attn_body32(
    u16* __restrict__ Ks, u16* __restrict__ Vs,
    const u16* __restrict__ Q, const u16* __restrict__ KV,
    const u16* __restrict__ Vt, u16* __restrict__ X,
    const int h, const int sc, const int qt, const int b)
{
  const int tid = threadIdx.x;
  const int lane = tid & 63, wv = tid >> 6;
  const int hi = lane >> 5, ql = lane & 31;

  const u16* qptr = Q + ((size_t)(b * 1024 + qt * 128 + wv * 32 + ql)) * 512
                      + (sc * 4 + h) * 64 + hi * 8;
  short8 qf[4];
#pragma unroll
  for (int t = 0; t < 4; ++t) qf[t] = *(const short8*)(qptr + t * 16);

  f32x16 acc0, acc1;
#pragma unroll
  for (int i = 0; i < 16; ++i) { acc0[i] = 0.0f; acc1[i] = 0.0f; }
  float l = 0.0f;

  const char* kB = (const char*)(KV + (size_t)b * NK * 512 + h * 64);
  const char* vB = (const char*)(Vt + (size_t)((b * 4 + h) * 64) * NK);
  uint32_t koffL[4], voffL[4];
#pragma unroll
  for (int s = 0; s < 4; ++s) {
    const int c = s * 256 + tid;
    { const int key = c >> 3, cp = c & 7;
      koffL[s] = key * 1024 + ((cp ^ (key & 7)) << 4); }
    { const int d = c >> 4, cp = c & 15;
      voffL[s] = d * (NK * 2) + ((cp ^ (d & 15)) << 4); }
  }

  const int sel = ((ql >> 2) ^ (ql >> 3)) & 1;
  const int kpi = ql ^ (sel ? 12 : 0);
  int kaddr[4];
#pragma unroll
  for (int t = 0; t < 4; ++t)
    kaddr[t] = kpi * 128 + (((t * 2 + hi) ^ (kpi & 7)) << 4);
  const int vx = ql & 15;

  constexpr int NT = NK / 128;
#define ISSUE_KV(kt_) { \
  const char* kT_ = kB + (size_t)(kt_) * 131072; \
  const char* vT_ = vB + (size_t)(kt_) * 256; \
  _Pragma("unroll") for (int s_ = 0; s_ < 4; ++s_) { \
    GLOAD16(kT_ + koffL[s_], (char*)Ks + (s_ * 256 + tid) * 16); \
    GLOAD16(vT_ + voffL[s_], (char*)Vs + (s_ * 256 + tid) * 16); } }

  ISSUE_KV(0);

  for (int kt = 0; kt < NT; ++kt) {
    asm volatile("s_waitcnt vmcnt(0)" ::: "memory");
    __builtin_amdgcn_s_barrier();
    __builtin_amdgcn_sched_barrier(0);

#pragma unroll
    for (int blk = 0; blk < 4; ++blk) {
      f32x16 sv;
#pragma unroll
      for (int i = 0; i < 16; ++i) sv[i] = 0.0f;
      __builtin_amdgcn_s_setprio(1);
#pragma unroll
      for (int t = 0; t < 4; ++t) {
        const short8 kf = *(const short8*)((const char*)Ks + blk * 4096 + kaddr[t]);
        sv = __builtin_amdgcn_mfma_f32_32x32x16_bf16(kf, qf[t], sv, 0, 0, 0);
      }
      __builtin_amdgcn_s_setprio(0);
#pragma unroll
      for (int i = 0; i < 16; ++i) {
        sv[i] = __builtin_amdgcn_exp2f(sv[i]);
        l += sv[i];
      }
#pragma unroll
      for (int sh = 0; sh < 2; ++sh) {
        u32x4 pw;
        asm("v_cvt_pk_bf16_f32 %0, %1, %2" : "=v"(pw[0]) : "v"(sv[8*sh+0]), "v"(sv[8*sh+1]));
        asm("v_cvt_pk_bf16_f32 %0, %1, %2" : "=v"(pw[1]) : "v"(sv[8*sh+2]), "v"(sv[8*sh+3]));
        asm("v_cvt_pk_bf16_f32 %0, %1, %2" : "=v"(pw[2]) : "v"(sv[8*sh+4]), "v"(sv[8*sh+5]));
        asm("v_cvt_pk_bf16_f32 %0, %1, %2" : "=v"(pw[3]) : "v"(sv[8*sh+6]), "v"(sv[8*sh+7]));
        const short8 pa = __builtin_bit_cast(short8, pw);
        const int step = blk * 2 + sh;
        const int vchunk = ((step * 2 + hi) ^ vx) << 4;
        __builtin_amdgcn_s_setprio(1);
        {
          const short8 vf0 = *(const short8*)((const char*)Vs + ql * 256 + vchunk);
          acc0 = __builtin_amdgcn_mfma_f32_32x32x16_bf16(pa, vf0, acc0, 0, 0, 0);
          const short8 vf1 = *(const short8*)((const char*)Vs + (32 + ql) * 256 + vchunk);
          acc1 = __builtin_amdgcn_mfma_f32_32x32x16_bf16(pa, vf1, acc1, 0, 0, 0);
        }
        __builtin_amdgcn_s_setprio(0);
      }
    }

    asm volatile("s_waitcnt lgkmcnt(0)" ::: "memory");
    __builtin_amdgcn_sched_barrier(0);
    __builtin_amdgcn_s_barrier();
    if (kt + 1 < NT) { ISSUE_KV(kt + 1); }
  }
#undef ISSUE_KV

  l += __shfl_xor(l, 32);
  const float inv = 1.0f / l;
  const long qbase = (long)b * 1024 + qt * 128 + wv * 32;
#pragma unroll
  for (int i = 0; i < 16; ++i) {
    const int row = (i & 3) + 8 * (i >> 2) + 4 * hi;
    const float ir = __shfl(inv, row);
    const long go = (qbase + row) * 512 + sc * 256 + h * 64 + ql;
    X[go]      = rne_bf16(acc0[i] * ir);
    X[go + 32] = rne_bf16(acc1[i] * ir);
  }
}

// Equal-duration grid: 256 s1-pair blocks (two heads x 8 tiles = 16) +
// 512 s2 blocks (16 tiles). 768 uniform blocks -> 3 blocks/CU throughout.
__global__ __launch_bounds__(256, 4) void attn_fused32_kernel(
    const u16* __restrict__ Q,
    const u16* __restrict__ KV1, const u16* __restrict__ KV2,
    const u16* __restrict__ Vt1, const u16* __restrict__ Vt2,
    u16* __restrict__ X)
{
  __shared__ __align__(16) u16 Ks[128 * 64];   // 128 keys x 64 d
  __shared__ __align__(16) u16 Vs[64 * 128];   // 64 d x 128 keys
  const int d = blockIdx.x;
  if (d < 256) {
    const int b = d & 15, qt = (d >> 4) & 7, hp = d >> 7;
    attn_body32<1024>(Ks, Vs, Q, KV1, Vt1, X, hp * 2,     0, qt, b);
    attn_body32<1024>(Ks, Vs, Q, KV1, Vt1, X, hp * 2 + 1, 0, qt, b);
  } else {
    const int e = d - 256;
    const int b = e & 15, qt = (e >> 4) & 7, h = e >> 7;
    attn_body32<2048>(Ks, Vs, Q, KV2, Vt2, X, h, 1, qt, b);
  }
}

// ---------------------------------------------------------------- launch
extern "C" void kernel_launch(void* const* d_in, const int* in_sizes, int n_in,
                              void* d_out, int out_size, void* d_ws, size_t ws_size,
                              hipStream_t stream) {
  const float* query   = (const float*)d_in[0];
  const float* key     = (const float*)d_in[1];
  const float* key_pos = (const float*)d_in[2];
  const float* xyz_up  = (const float*)d_in[4];
  const float* Wq      = (const float*)d_in[5];
  const float* Wkv1    = (const float*)d_in[6];
  const float* Wkv2    = (const float*)d_in[7];
  const float* fp_w    = (const float*)d_in[8];
  const float* fp_b    = (const float*)d_in[9];
  const float* proj_w  = (const float*)d_in[10];
  const float* proj_b  = (const float*)d_in[11];

  char* ws = (char*)d_ws;
  const size_t MB = 1024 * 1024;
  u16*  Qa    = (u16*)(ws + 0);          // 16MB bf16 query; later X
  u16*  Ka    = (u16*)(ws + 16 * MB);    // 16MB bf16 key
  u16*  Qb    = (u16*)(ws + 32 * MB);    // 16MB
  u16*  KV1   = (u16*)(ws + 48 * MB);    // 16MB (K half valid)
  u16*  IN2   = (u16*)(ws + 64 * MB);    // 32MB interp; later KV2 (K half)
  u16*  KEY2  = (u16*)(ws + 96 * MB);    // 32MB
  u16*  Vt1   = (u16*)(ws + 128 * MB);   //  8MB
  u16*  Vt2   = (u16*)(ws + 136 * MB);   // 16MB
  u16*  Wq2   = (u16*)(ws + 152 * MB);
  u16*  Wkv12 = (u16*)(ws + 152 * MB + 512 * 1024);
  u16*  proj2 = (u16*)(ws + 153 * MB);
  u16*  fpwb  = (u16*)(ws + 153 * MB + 512 * 1024);
  u16*  wkv2b = (u16*)(ws + 154 * MB);
  int*  idxb  = (int*)(ws + 155 * MB);
  float* wb   = (float*)(ws + 156 * MB);
  u16*  KV2   = IN2;
  u16*  X     = Qa;

  // 1. conversions + 3-NN
  prep_kernel<<<dim3(10880), 256, 0, stream>>>(
      query, Qa, key, Ka, Wq, Wkv1, proj_w, fp_w, Wkv2,
      Wq2, Wkv12, proj2, fpwb, wkv2b, key_pos, xyz_up, idxb, wb);
  // 2. inverse-distance interpolation
  interp_bf16_kernel<<<dim3(8192), 256, 0, stream>>>(Ka, idxb, wb, IN2);
  // 3. q-GEMM + kv1-GEMM (Vt1 folded) + fp-GEMM (homogeneous merge)
  gemm_mega_kernel<<<dim3(2048), 256, 0, stream>>>(
      Qa, Wq2, Qb, Ka, Wkv12, KV1, Vt1, IN2, fpwb, fp_b, KEY2);
  // 4. kv2-GEMM (Vt2 folded)
  kv2_kernel<<<dim3(1024), 256, 0, stream>>>(KEY2, wkv2b, KV2, Vt2);
  // 5. fused attention (equal-duration 768-block grid) -> X
  attn_fused32_kernel<<<dim3(768), 256, 0, stream>>>(Qb, KV1, KV2, Vt1, Vt2, X);
  // 6. output projection + final transpose
  gemm_proj64_kernel<<<dim3(1024), 256, 0, stream>>>(X, proj2, proj_b, (float*)d_out);
}